// Round 1
// baseline (188.567 us; speedup 1.0000x reference)
//
#include <hip/hip_runtime.h>

// CRF NLL: forward algorithm (linear-space, rescaled) + gold score.
// B=128 batches, S=512 steps, T=36 states (START=34, END=35).
// One wave (64 lanes) per batch; lane j owns state j.
//   q_j = exp(alpha_j - C);  step: q' = (q . M) * exp(f_t),  M = exp(trans)
// M columns live in 36 VGPRs per lane; dot product via v_readlane broadcast.

namespace {
constexpr int kB = 128;
constexpr int kS = 512;
constexpr int kT = 36;
constexpr int kStart = 34;
constexpr int kEnd = 35;

__device__ __forceinline__ float readlane_f(float v, int lane) {
    return __builtin_bit_cast(float, __builtin_amdgcn_readlane(__builtin_bit_cast(int, v), lane));
}

__device__ __forceinline__ float wave_max(float v) {
#pragma unroll
    for (int off = 32; off; off >>= 1) v = fmaxf(v, __shfl_xor(v, off, 64));
    return v;
}

__device__ __forceinline__ float wave_sum(float v) {
#pragma unroll
    for (int off = 32; off; off >>= 1) v += __shfl_xor(v, off, 64);
    return v;
}

__device__ __forceinline__ int wave_sum_i(int v) {
#pragma unroll
    for (int off = 32; off; off >>= 1) v += __shfl_xor(v, off, 64);
    return v;
}

__global__ __launch_bounds__(64, 1) void crf_nll_kernel(
    const float* __restrict__ feats,   // (B,S,T)
    const float* __restrict__ trans,   // (T,T)  [i,j] = prev i -> cur j
    const int* __restrict__ mask,      // (B,S)  contiguous prefix
    const int* __restrict__ tags,      // (B,S)
    float* __restrict__ out) {         // scalar
    const int b = blockIdx.x;
    const int j = threadIdx.x;  // lane = state index (j < 36 active for states)
    const float* fb = feats + (size_t)b * kS * kT;
    const int* mb = mask + b * kS;
    const int* tb = tags + b * kS;

    // ---- sequence length (mask is a contiguous prefix of ones) ----
    int len = 0;
    for (int k = j; k < kS; k += 64) len += mb[k];
    len = wave_sum_i(len);  // all lanes hold len; len in [S/2, S]

    // ---- per-lane column of M = exp(trans): Mcol[i] = exp(trans[i][j]) ----
    float Mcol[kT];
    float ME = 0.f;  // exp(trans[j][END]) for the final reduction
    if (j < kT) {
#pragma unroll
        for (int i = 0; i < kT; ++i) Mcol[i] = __expf(trans[i * kT + j]);
        ME = __expf(trans[j * kT + kEnd]);
    } else {
#pragma unroll
        for (int i = 0; i < kT; ++i) Mcol[i] = 0.f;
    }

    // ---- init: alpha0 = feats[b,0,:] + trans[START,:] ----
    float a0 = -1e30f;
    if (j < kT) a0 = fb[j] + trans[kStart * kT + j];
    float C = wave_max(a0);
    float q = __expf(a0 - C);  // lanes >= 36 -> exp(-huge) = 0

    // ---- main scan t = 1 .. len-1, depth-8 register prefetch of feats ----
    const int tmax = len;
    float fpf[8];
#pragma unroll
    for (int p = 0; p < 8; ++p) fpf[p] = (j < kT) ? fb[(1 + p) * kT + j] : 0.f;

    int t = 1;
    while (t + 8 <= tmax) {
#pragma unroll
        for (int u = 0; u < 8; ++u) {
            const float f = fpf[u];
            int tn = t + u + 8;
            if (tn > kS - 1) tn = kS - 1;  // clamp: value unused past len
            fpf[u] = (j < kT) ? fb[tn * kT + j] : 0.f;

            float v0 = 0.f, v1 = 0.f, v2 = 0.f, v3 = 0.f;
#pragma unroll
            for (int i = 0; i < kT; i += 4) {
                v0 = fmaf(readlane_f(q, i + 0), Mcol[i + 0], v0);
                v1 = fmaf(readlane_f(q, i + 1), Mcol[i + 1], v1);
                v2 = fmaf(readlane_f(q, i + 2), Mcol[i + 2], v2);
                v3 = fmaf(readlane_f(q, i + 3), Mcol[i + 3], v3);
            }
            q = ((v0 + v1) + (v2 + v3)) * __expf(f);

            if (((t + u) & 3) == 0) {  // renorm every 4 steps (range safety)
                const float m = wave_max(q);
                q *= __builtin_amdgcn_rcpf(m);
                C += __logf(m);
            }
        }
        t += 8;
    }
    for (; t < tmax; ++t) {  // tail (< 8 iters; loads are cache-warm)
        const float f = (j < kT) ? fb[t * kT + j] : 0.f;
        float v0 = 0.f, v1 = 0.f, v2 = 0.f, v3 = 0.f;
#pragma unroll
        for (int i = 0; i < kT; i += 4) {
            v0 = fmaf(readlane_f(q, i + 0), Mcol[i + 0], v0);
            v1 = fmaf(readlane_f(q, i + 1), Mcol[i + 1], v1);
            v2 = fmaf(readlane_f(q, i + 2), Mcol[i + 2], v2);
            v3 = fmaf(readlane_f(q, i + 3), Mcol[i + 3], v3);
        }
        q = ((v0 + v1) + (v2 + v3)) * __expf(f);
        if ((t & 3) == 0) {
            const float m = wave_max(q);
            q *= __builtin_amdgcn_rcpf(m);
            C += __logf(m);
        }
    }

    // ---- forward score: C + log(sum_i q_i * exp(trans[i][END])) ----
    const float ssum = wave_sum(q * ME);
    const float forward_b = C + __logf(ssum);

    // ---- gold score (parallel over time steps) ----
    float g = 0.f;
    for (int k = j; k < kS; k += 64) {
        if (k < len) {
            const int tg = tb[k];
            const int pv = (k == 0) ? kStart : tb[k - 1];
            g += fb[(size_t)k * kT + tg] + trans[pv * kT + tg];
        }
    }
    g = wave_sum(g);

    if (j == 0) {
        g += trans[tb[len - 1] * kT + kEnd];
        atomicAdd(out, (forward_b - g) * (1.0f / kB));
    }
}

}  // namespace

extern "C" void kernel_launch(void* const* d_in, const int* in_sizes, int n_in,
                              void* d_out, int out_size, void* d_ws, size_t ws_size,
                              hipStream_t stream) {
    const float* feats = (const float*)d_in[0];
    const float* trans = (const float*)d_in[1];
    const int* mask = (const int*)d_in[2];
    const int* tags = (const int*)d_in[3];
    float* out = (float*)d_out;

    hipMemsetAsync(out, 0, sizeof(float), stream);
    crf_nll_kernel<<<dim3(kB), dim3(64), 0, stream>>>(feats, trans, mask, tags, out);
}